// Round 1
// baseline (681.814 us; speedup 1.0000x reference)
//
#include <hip/hip_runtime.h>

// Problem constants
#define CI_    32
#define CO_    32
#define H_     256
#define W_     512
#define NPART_ 8
#define HP_    32
#define NTAP   13   // valid taps after group mask: ky0 kx0-4, ky1 kx0-4, ky2 kx0-2

// ---------------------------------------------------------------------------
// Prep: pack masked weights into d_ws as [ci][tap][co] (contiguous co for
// wide uniform scalar loads in the main kernel). Center tap (ky=2,kx=2) is
// pre-masked: gin<=gout (HIDDEN) else 0.
// ---------------------------------------------------------------------------
__global__ __launch_bounds__(256) void prep_weights(const float* __restrict__ w,
                                                    float* __restrict__ wpk) {
    int idx = blockIdx.x * 256 + threadIdx.x;
    if (idx >= CI_ * NTAP * CO_) return;
    int co = idx & 31;
    int t  = (idx >> 5) % NTAP;
    int ci = idx / (NTAP * 32);
    int ky, kx;
    if (t < 5)       { ky = 0; kx = t;      }
    else if (t < 10) { ky = 1; kx = t - 5;  }
    else             { ky = 2; kx = t - 10; }
    float v = w[((co * CI_ + ci) * 5 + ky) * 5 + kx];
    if (ky == 2 && kx == 2 && ((ci >> 2) > (co >> 2))) v = 0.f;
    wpk[idx] = v;
}

// Load NK aligned float2 covering cols [c0-2, c0-2+2*NK) of one input row,
// with bounds + width masking. ok==false => partition top padding (zeros).
template <int NK>
__device__ __forceinline__ void load_row(float* v, const float* __restrict__ rp,
                                         bool ok, int c0, int wp) {
#pragma unroll
    for (int k = 0; k < NK; ++k) {
        int col = c0 - 2 + 2 * k;
        float2 t = make_float2(0.f, 0.f);
        if (ok && col >= 0 && col < W_)
            t = *reinterpret_cast<const float2*>(rp + col);
        v[2 * k]     = (col     < wp) ? t.x : 0.f;
        v[2 * k + 1] = (col + 1 < wp) ? t.y : 0.f;
    }
}

// ---------------------------------------------------------------------------
// Main: block = one (row r, batch b). 256 threads, thread = 2 adjacent cols,
// all 32 output channels. Weights via uniform scalar loads from packed d_ws.
// ---------------------------------------------------------------------------
__global__ __launch_bounds__(256) void conv_main(const float* __restrict__ x,
                                                 const float* __restrict__ bias,
                                                 const float* __restrict__ alpha,
                                                 const int* __restrict__ widths,
                                                 const float* __restrict__ wpk,
                                                 float* __restrict__ out) {
    const int r  = blockIdx.x;            // global row 0..255
    const int b  = blockIdx.y;            // batch 0..7
    const int p  = r >> 5;                // partition
    const int lr = r & 31;                // local row in partition
    const int wp = widths[p];             // valid width for this partition
    const int c0 = threadIdx.x * 2;

    float* outp = out + (((size_t)(b * CO_)) * H_ + r) * W_ + c0;

    if (c0 >= wp) {
        // whole 2-pixel strip invalid: write zeros for all co
        float2 z = make_float2(0.f, 0.f);
#pragma unroll
        for (int co = 0; co < CO_; ++co)
            *reinterpret_cast<float2*>(outp + (size_t)co * (H_ * W_)) = z;
        return;
    }

    float acc0[CO_], acc1[CO_];
#pragma unroll
    for (int co = 0; co < CO_; ++co) {
        float bv = bias[co];
        acc0[co] = bv;
        acc1[co] = bv;
    }

    const bool rowm2 = (lr >= 2);
    const bool rowm1 = (lr >= 1);
    const float* xrow = x + (((size_t)(b * CI_)) * H_ + r) * W_;  // ci=0, row r

    for (int ci = 0; ci < CI_; ++ci) {
        const float* xr0 = xrow + (size_t)ci * (H_ * W_);
        float xa[6], xb[6], xc[4];
        load_row<3>(xa, xr0 - 2 * W_, rowm2, c0, wp);   // row r-2 (dy=-2)
        load_row<3>(xb, xr0 - 1 * W_, rowm1, c0, wp);   // row r-1 (dy=-1)
        load_row<2>(xc, xr0,          true,  c0, wp);   // row r   (dy= 0)

        const float* wci = wpk + ci * (NTAP * 32);
#pragma unroll
        for (int t = 0; t < NTAP; ++t) {
            const float* xr;
            int kx;
            if (t < 5)       { xr = xa; kx = t;      }
            else if (t < 10) { xr = xb; kx = t - 5;  }
            else             { xr = xc; kx = t - 10; }
            const float x0 = xr[kx];
            const float x1 = xr[kx + 1];
            const float* wt = wci + t * 32;
#pragma unroll
            for (int co = 0; co < CO_; ++co) {
                const float wv = wt[co];   // block-uniform -> s_load
                acc0[co] = fmaf(wv, x0, acc0[co]);
                acc1[co] = fmaf(wv, x1, acc1[co]);
            }
        }
    }

    const bool ok1 = (c0 + 1 < wp);
#pragma unroll
    for (int co = 0; co < CO_; ++co) {
        const float a = alpha[co];
        float y0 = acc0[co];
        float y1 = acc1[co];
        y0 = (y0 > 0.f) ? y0 : a * y0;
        y1 = (y1 > 0.f) ? y1 : a * y1;
        if (!ok1) y1 = 0.f;
        *reinterpret_cast<float2*>(outp + (size_t)co * (H_ * W_)) = make_float2(y0, y1);
    }
}

extern "C" void kernel_launch(void* const* d_in, const int* in_sizes, int n_in,
                              void* d_out, int out_size, void* d_ws, size_t ws_size,
                              hipStream_t stream) {
    const float* x      = (const float*)d_in[0];
    const float* weight = (const float*)d_in[1];
    const float* bias   = (const float*)d_in[2];
    const float* alpha  = (const float*)d_in[3];
    const int*   widths = (const int*)d_in[4];
    float*       out    = (float*)d_out;
    float*       wpk    = (float*)d_ws;   // 13312 floats = 53 KB packed weights

    (void)in_sizes; (void)n_in; (void)out_size; (void)ws_size;

    prep_weights<<<dim3((CI_ * NTAP * CO_ + 255) / 256), 256, 0, stream>>>(weight, wpk);
    conv_main<<<dim3(H_, 8), 256, 0, stream>>>(x, bias, alpha, widths, wpk, out);
}

// Round 2
// 272.357 us; speedup vs baseline: 2.5034x; 2.5034x over previous
//
#include <hip/hip_runtime.h>

typedef __attribute__((ext_vector_type(8))) short  short8;   // 8 bf16 = 4 VGPRs (MFMA A/B frag)
typedef __attribute__((ext_vector_type(4))) float  f32x4;    // MFMA C/D frag

#define NTAP 13      // ky0: dx0-4 (row r-2), ky1: dx0-4 (row r-1), ky2: dx0-2 (row r, dx2=center masked)
#define COLS 260     // 256 cols + 2 halo each side
#define SLOT 1040    // uint4 (16B chunks) per LDS row-slot = COLS*4

__device__ __forceinline__ unsigned short f2bf(float f) {   // fp32 -> bf16 RNE
    unsigned u = __builtin_bit_cast(unsigned, f);
    return (unsigned short)((u + 0x7fffu + ((u >> 16) & 1u)) >> 16);
}

// ---------------------------------------------------------------------------
// Prep: pack masked weights into MFMA A-fragment layout, bf16.
// wf[(t*2+a)*64 + lane] (16B) holds, for j=0..7:
//   w[co = a*16 + (lane&15)][ci = (lane>>4)*8 + j][tap t]   (center tap masked)
// A-frag mapping: A[m=co][k=ci], m = lane&15, k = (lane>>4)*8 + j.
// (Any consistent k-slot permutation is fine as long as A and B agree.)
// ---------------------------------------------------------------------------
__global__ __launch_bounds__(256) void prep_wfrag(const float* __restrict__ w,
                                                  uint4* __restrict__ wf) {
    int idx = blockIdx.x * 256 + threadIdx.x;     // (t*2+a)*64 + lane
    if (idx >= NTAP * 2 * 64) return;
    int lane = idx & 63;
    int a    = (idx >> 6) & 1;
    int t    = idx >> 7;
    int co = a * 16 + (lane & 15);
    int g  = lane >> 4;
    int ky, kx;
    if (t < 5)       { ky = 0; kx = t; }
    else if (t < 10) { ky = 1; kx = t - 5; }
    else             { ky = 2; kx = t - 10; }
    unsigned short h[8];
#pragma unroll
    for (int j = 0; j < 8; ++j) {
        int ci = g * 8 + j;
        float v = w[((co * 32 + ci) * 5 + ky) * 5 + kx];
        if (ky == 2 && kx == 2 && ((ci >> 2) > (co >> 2))) v = 0.f;  // HIDDEN: gin<=gout visible
        h[j] = f2bf(v);
    }
    uint4 val;
    val.x = (unsigned)h[0] | ((unsigned)h[1] << 16);
    val.y = (unsigned)h[2] | ((unsigned)h[3] << 16);
    val.z = (unsigned)h[4] | ((unsigned)h[5] << 16);
    val.w = (unsigned)h[6] | ((unsigned)h[7] << 16);
    wf[idx] = val;
}

// ---------------------------------------------------------------------------
// Main: implicit-GEMM masked conv via mfma_f32_16x16x32_bf16.
// Block = (b, partition p, row-group rg of 8 rows, col-half). 4 waves.
// Wave w: stages ci-chunk w of each row; computes cols [c0+64w, c0+64w+64).
// LDS: rolling 3-row buffer, [slot][col][ci-chunk ^ ((col>>1)&3)] 16B chunks.
// GEMM: D[co][pix] = sum_ci W[co][ci] * X[ci][pix]  per tap, K=32=ci.
// ---------------------------------------------------------------------------
__global__ __launch_bounds__(256, 2) void conv_mfma(
    const float* __restrict__ x, const float* __restrict__ bias,
    const float* __restrict__ alpha, const int* __restrict__ widths,
    const uint4* __restrict__ wf, float* __restrict__ out)
{
    const int p    = blockIdx.y;
    const int b    = blockIdx.z;
    const int half = blockIdx.x & 1;
    const int rg   = blockIdx.x >> 1;
    const int r0   = p * 32 + rg * 8;
    const int c0   = half * 256;
    const int wp   = widths[p];
    const int tid  = threadIdx.x;
    const int w    = tid >> 6;      // wave = staged ci-chunk
    const int lane = tid & 63;

    if (c0 >= wp) {   // whole block right of valid width: write zeros, done
        const f32x4 z = {0.f, 0.f, 0.f, 0.f};
        for (int i = tid; i < 32 * 8 * 64; i += 256) {
            int c4 = i & 63;
            int r  = (i >> 6) & 7;
            int co = i >> 9;
            *reinterpret_cast<f32x4*>(out + ((((size_t)b * 32 + co) * 256 + (r0 + r)) << 9)
                                      + c0 + c4 * 4) = z;
        }
        return;
    }

    __shared__ uint4 lds[3 * SLOT];

    // W fragments: 26 x 16B from packed table (L1/L2-hit), kept in VGPRs
    short8 wreg[NTAP][2];
#pragma unroll
    for (int t = 0; t < NTAP; ++t)
#pragma unroll
        for (int a = 0; a < 2; ++a)
            wreg[t][a] = reinterpret_cast<const short8*>(wf)[(t * 2 + a) * 64 + lane];

    const int g  = lane >> 4;      // compute-side k-chunk / D-row group
    const int rr = lane & 15;      // compute-side pixel within frag
    const f32x4 bias0 = *reinterpret_cast<const f32x4*>(bias  + 4 * g);
    const f32x4 bias1 = *reinterpret_cast<const f32x4*>(bias  + 16 + 4 * g);
    const f32x4 al0   = *reinterpret_cast<const f32x4*>(alpha + 4 * g);
    const f32x4 al1   = *reinterpret_cast<const f32x4*>(alpha + 16 + 4 * g);

    // stage row (r0-2+stagei) into slot stagei%3; zero above partition top / beyond width
    auto stage = [&](int stagei) {
        const int rabs = r0 - 2 + stagei;
        const int slot = stagei % 3;
        const bool vr  = (rabs >= p * 32);
        const float* xg = x + (((size_t)(b * 32 + w * 8) * 256 + (vr ? rabs : 0)) << 9);
        for (int c = lane; c < COLS; c += 64) {
            const int gcol = c0 - 2 + c;
            const bool ok = vr && (gcol >= 0) && (gcol < wp);
            unsigned short h[8];
            if (ok) {
#pragma unroll
                for (int j = 0; j < 8; ++j)
                    h[j] = f2bf(xg[((size_t)j << 17) + gcol]);   // j*H*W = j<<17
            } else {
#pragma unroll
                for (int j = 0; j < 8; ++j) h[j] = 0;
            }
            uint4 v;
            v.x = (unsigned)h[0] | ((unsigned)h[1] << 16);
            v.y = (unsigned)h[2] | ((unsigned)h[3] << 16);
            v.z = (unsigned)h[4] | ((unsigned)h[5] << 16);
            v.w = (unsigned)h[6] | ((unsigned)h[7] << 16);
            lds[slot * SLOT + c * 4 + (w ^ ((c >> 1) & 3))] = v;   // swizzled 16B chunk
        }
    };

    stage(0);   // row r0-2
    stage(1);   // row r0-1

#pragma unroll 1
    for (int ir = 0; ir < 8; ++ir) {
        stage(ir + 2);          // row r0+ir -> slot (ir+2)%3
        __syncthreads();

        const int r  = r0 + ir;
        const int s2 = ir % 3;          // row r-2
        const int s1 = (ir + 1) % 3;    // row r-1
        const int s0 = (ir + 2) % 3;    // row r

        f32x4 acc[4][2];
#pragma unroll
        for (int pf = 0; pf < 4; ++pf) { acc[pf][0] = bias0; acc[pf][1] = bias1; }

#pragma unroll
        for (int t = 0; t < NTAP; ++t) {
            const int slot = (t < 5) ? s2 : (t < 10) ? s1 : s0;
            const int dx   = (t < 5) ? t : (t < 10) ? (t - 5) : (t - 10);
#pragma unroll
            for (int pf = 0; pf < 4; ++pf) {
                const int c = 64 * w + 16 * pf + rr + dx;
                const short8 xf = *reinterpret_cast<const short8*>(
                    &lds[slot * SLOT + c * 4 + (g ^ ((c >> 1) & 3))]);
                acc[pf][0] = __builtin_amdgcn_mfma_f32_16x16x32_bf16(wreg[t][0], xf, acc[pf][0], 0, 0, 0);
                acc[pf][1] = __builtin_amdgcn_mfma_f32_16x16x32_bf16(wreg[t][1], xf, acc[pf][1], 0, 0, 0);
            }
        }

        // epilogue: leaky-relu, width mask, store (D: co = 16a+4g+j, col = rr)
#pragma unroll
        for (int pf = 0; pf < 4; ++pf) {
            const int col = c0 + 64 * w + 16 * pf + rr;
            const bool vc = (col < wp);
#pragma unroll
            for (int a = 0; a < 2; ++a) {
                const f32x4 d  = acc[pf][a];
                const f32x4 al = a ? al1 : al0;
                const int cob  = a * 16 + 4 * g;
#pragma unroll
                for (int j = 0; j < 4; ++j) {
                    float y = d[j];
                    y = (y > 0.f) ? y : al[j] * y;
                    y = vc ? y : 0.f;
                    out[((((size_t)b * 32 + cob + j) * 256 + r) << 9) + col] = y;
                }
            }
        }
        __syncthreads();   // protect slot reuse by next stage()
    }
}

extern "C" void kernel_launch(void* const* d_in, const int* in_sizes, int n_in,
                              void* d_out, int out_size, void* d_ws, size_t ws_size,
                              hipStream_t stream) {
    const float* x      = (const float*)d_in[0];
    const float* weight = (const float*)d_in[1];
    const float* bias   = (const float*)d_in[2];
    const float* alpha  = (const float*)d_in[3];
    const int*   widths = (const int*)d_in[4];
    float*       out    = (float*)d_out;
    uint4*       wfrag  = (uint4*)d_ws;    // 13*2*64*16B = 26.6 KB packed W-fragments

    (void)in_sizes; (void)n_in; (void)out_size; (void)ws_size;

    prep_wfrag<<<dim3(7), 256, 0, stream>>>(weight, wfrag);
    conv_mfma<<<dim3(8, 8, 8), 256, 0, stream>>>(x, bias, alpha, widths, wfrag, out);
}